// Round 1
// baseline (1342.999 us; speedup 1.0000x reference)
//
#include <hip/hip_runtime.h>
#include <stdint.h>

#define HIDD 128
#define NNODES 100000
#define NEDGES 800000

typedef short s16x8 __attribute__((ext_vector_type(8)));
typedef float f32x4 __attribute__((ext_vector_type(4)));

__device__ __forceinline__ short f2bf(float f) {
  union { float f; unsigned u; } v; v.f = f;
  return (short)((v.u + 0x7fffu + ((v.u >> 16) & 1u)) >> 16);
}
__device__ __forceinline__ short4 cvt4(float4 v) {
  short4 s; s.x = f2bf(v.x); s.y = f2bf(v.y); s.z = f2bf(v.z); s.w = f2bf(v.w);
  return s;
}

// ---------- prep: h -> bf16 ----------
__global__ void k_prep_h(const float4* __restrict__ h4, short4* __restrict__ hb4, int n4) {
  int stride = gridDim.x * blockDim.x;
  for (int i = blockIdx.x * blockDim.x + threadIdx.x; i < n4; i += stride)
    hb4[i] = cvt4(h4[i]);
}

// ---------- prep: weights -> bf16, transposed to [out][in] ----------
__global__ void k_prep_w(const float* __restrict__ w1e, const float* __restrict__ w2e,
                         const float* __restrict__ w1u, const float* __restrict__ w2u,
                         short* __restrict__ w1et, short* __restrict__ w2et,
                         short* __restrict__ w1ut, short* __restrict__ w2ut) {
  int i = blockIdx.x * 256 + threadIdx.x;
  if (i < 49152) {               // [384][128] -> [128][384]
    int k = i >> 7, n = i & 127;
    w1et[n * 384 + k] = f2bf(w1e[i]);
    w1ut[n * 384 + k] = f2bf(w1u[i]);
  } else {
    int j = i - 49152;
    if (j < 16384) {             // [128][128] -> [128][128]
      int k = j >> 7, n = j & 127;
      w2et[n * 128 + k] = f2bf(w2e[j]);
      w2ut[n * 128 + k] = f2bf(w2u[j]);
    }
  }
}

// ---------- edge: X=[h[src]|h[dst]|edge_x] -> 2-layer MLP -> scatter-add ----------
__global__ __launch_bounds__(256, 1)
void k_edge(const short* __restrict__ hb, const int* __restrict__ eidx,
            const float* __restrict__ ex,
            const short* __restrict__ w1t, const short* __restrict__ w2t,
            const float* __restrict__ b1g, const float* __restrict__ b2g,
            float* __restrict__ inc, float* __restrict__ outg,
            float* __restrict__ indeg, float* __restrict__ outdeg) {
  __shared__ __align__(16) char smem[151040];
  short (*Xs)[392]  = (short (*)[392])smem;            // 64x392 bf16 = 50176 B
  short (*Ws)[392]  = (short (*)[392])(smem + 50176);  // 128x392 bf16 = 100352 B
  short (*Hs)[136]  = (short (*)[136])smem;            // hidden reuses X region
  short (*W2s)[136] = (short (*)[136])(smem + 50176);  // W2 reuses W region
  int* srcs = (int*)(smem + 150528);
  int* dsts = srcs + 64;

  const int tid = threadIdx.x;
  const int base = blockIdx.x * 64;

  if (tid < 128) {
    int r = tid & 63;
    if (tid < 64) srcs[r] = eidx[base + r];
    else          dsts[r] = eidx[NEDGES + base + r];
  }
  __syncthreads();

  // gather h[src], h[dst] (bf16, 16B chunks)
  for (int u = tid; u < 64 * 32; u += 256) {
    int r = u >> 5, c = u & 31;
    int node = (c < 16) ? srcs[r] : dsts[r];
    *(int4*)&Xs[r][c * 8] = *(const int4*)(hb + (long)node * 128 + (c & 15) * 8);
  }
  // edge_x fp32 -> bf16
  for (int u = tid; u < 64 * 32; u += 256) {
    int r = u >> 5, q = u & 31;
    float4 v = *(const float4*)(ex + (long)(base + r) * 128 + q * 4);
    *(short4*)&Xs[r][256 + q * 4] = cvt4(v);
  }
  // stage W1^T [128][384]
  for (int u = tid; u < 128 * 48; u += 256) {
    int r = u / 48, c = u - r * 48;
    *(int4*)&Ws[r][c * 8] = *(const int4*)(w1t + r * 384 + c * 8);
  }
  // degrees
  if (tid < 64) {
    atomicAdd(&outdeg[srcs[tid]], 1.0f);
    atomicAdd(&indeg[dsts[tid]], 1.0f);
  }
  __syncthreads();

  const int wave = tid >> 6, lane = tid & 63;
  const int lg = lane >> 4, lr = lane & 15;
  const int koff = lg * 8;
  const int c0 = wave * 32 + lr, c1 = wave * 32 + 16 + lr;

  // layer 1: [64,384] @ [384,128]
  f32x4 acc[4][2] = {};
  for (int kk = 0; kk < 12; ++kk) {
    int k0 = kk * 32 + koff;
    s16x8 bf0 = *(const s16x8*)&Ws[c0][k0];
    s16x8 bf1 = *(const s16x8*)&Ws[c1][k0];
#pragma unroll
    for (int m = 0; m < 4; ++m) {
      s16x8 a = *(const s16x8*)&Xs[m * 16 + lr][k0];
      acc[m][0] = __builtin_amdgcn_mfma_f32_16x16x32_bf16(a, bf0, acc[m][0], 0, 0, 0);
      acc[m][1] = __builtin_amdgcn_mfma_f32_16x16x32_bf16(a, bf1, acc[m][1], 0, 0, 0);
    }
  }
  float bias1_0 = b1g[c0], bias1_1 = b1g[c1];
  __syncthreads();   // all waves done reading Xs/Ws

  // hidden (bias+relu) -> bf16 LDS
#pragma unroll
  for (int m = 0; m < 4; ++m)
#pragma unroll
    for (int r2 = 0; r2 < 4; ++r2) {
      int row = m * 16 + lg * 4 + r2;
      Hs[row][c0] = f2bf(fmaxf(acc[m][0][r2] + bias1_0, 0.f));
      Hs[row][c1] = f2bf(fmaxf(acc[m][1][r2] + bias1_1, 0.f));
    }
  // stage W2^T [128][128]
  for (int u = tid; u < 128 * 16; u += 256) {
    int r = u >> 4, c = u & 15;
    *(int4*)&W2s[r][c * 8] = *(const int4*)(w2t + r * 128 + c * 8);
  }
  __syncthreads();

  // layer 2: [64,128] @ [128,128]
  f32x4 acc2[4][2] = {};
  for (int kk = 0; kk < 4; ++kk) {
    int k0 = kk * 32 + koff;
    s16x8 bf0 = *(const s16x8*)&W2s[c0][k0];
    s16x8 bf1 = *(const s16x8*)&W2s[c1][k0];
#pragma unroll
    for (int m = 0; m < 4; ++m) {
      s16x8 a = *(const s16x8*)&Hs[m * 16 + lr][k0];
      acc2[m][0] = __builtin_amdgcn_mfma_f32_16x16x32_bf16(a, bf0, acc2[m][0], 0, 0, 0);
      acc2[m][1] = __builtin_amdgcn_mfma_f32_16x16x32_bf16(a, bf1, acc2[m][1], 0, 0, 0);
    }
  }
  float bias2_0 = b2g[c0], bias2_1 = b2g[c1];

  // scatter-add messages to inc[dst], outg[src]
#pragma unroll
  for (int m = 0; m < 4; ++m)
#pragma unroll
    for (int r2 = 0; r2 < 4; ++r2) {
      int row = m * 16 + lg * 4 + r2;
      int s = srcs[row], d = dsts[row];
      float v0 = acc2[m][0][r2] + bias2_0;
      float v1 = acc2[m][1][r2] + bias2_1;
      atomicAdd(&outg[(long)s * 128 + c0], v0);
      atomicAdd(&outg[(long)s * 128 + c1], v1);
      atomicAdd(&inc[(long)d * 128 + c0], v0);
      atomicAdd(&inc[(long)d * 128 + c1], v1);
    }
}

// ---------- node: X=[h|inc/deg|outg/deg] -> 2-layer MLP -> residual+LN ----------
__global__ __launch_bounds__(256, 1)
void k_node(const float* __restrict__ h, const float* __restrict__ inc,
            const float* __restrict__ outg, const float* __restrict__ indeg,
            const float* __restrict__ outdeg,
            const short* __restrict__ w1t, const short* __restrict__ w2t,
            const float* __restrict__ b1g, const float* __restrict__ b2g,
            const float* __restrict__ lng, const float* __restrict__ lnb,
            float* __restrict__ out) {
  __shared__ __align__(16) char smem[151040];
  short (*Xs)[392]  = (short (*)[392])smem;
  short (*Ws)[392]  = (short (*)[392])(smem + 50176);
  short (*Hs)[136]  = (short (*)[136])smem;
  short (*W2s)[136] = (short (*)[136])(smem + 50176);
  float (*Xf)[132]  = (float (*)[132])(smem + 50176 + 34816);  // 64x132 f32 = 33792 B
  float* invi = (float*)(smem + 150528);
  float* invo = invi + 64;

  const int tid = threadIdx.x;
  const int base = blockIdx.x * 64;

  if (tid < 64) {
    int node = min(base + tid, NNODES - 1);
    invi[tid] = 1.f / fmaxf(indeg[node], 1.f);
    invo[tid] = 1.f / fmaxf(outdeg[node], 1.f);
  }
  __syncthreads();

  for (int u = tid; u < 64 * 32; u += 256) {
    int r = u >> 5, q = u & 31;
    long node = min(base + r, NNODES - 1);
    float4 v = *(const float4*)(h + node * 128 + q * 4);
    *(short4*)&Xs[r][q * 4] = cvt4(v);
  }
  for (int u = tid; u < 64 * 32; u += 256) {
    int r = u >> 5, q = u & 31;
    long node = min(base + r, NNODES - 1);
    float4 v = *(const float4*)(inc + node * 128 + q * 4);
    float s = invi[r];
    v.x *= s; v.y *= s; v.z *= s; v.w *= s;
    *(short4*)&Xs[r][128 + q * 4] = cvt4(v);
  }
  for (int u = tid; u < 64 * 32; u += 256) {
    int r = u >> 5, q = u & 31;
    long node = min(base + r, NNODES - 1);
    float4 v = *(const float4*)(outg + node * 128 + q * 4);
    float s = invo[r];
    v.x *= s; v.y *= s; v.z *= s; v.w *= s;
    *(short4*)&Xs[r][256 + q * 4] = cvt4(v);
  }
  for (int u = tid; u < 128 * 48; u += 256) {
    int r = u / 48, c = u - r * 48;
    *(int4*)&Ws[r][c * 8] = *(const int4*)(w1t + r * 384 + c * 8);
  }
  __syncthreads();

  const int wave = tid >> 6, lane = tid & 63;
  const int lg = lane >> 4, lr = lane & 15;
  const int koff = lg * 8;
  const int c0 = wave * 32 + lr, c1 = wave * 32 + 16 + lr;

  f32x4 acc[4][2] = {};
  for (int kk = 0; kk < 12; ++kk) {
    int k0 = kk * 32 + koff;
    s16x8 bf0 = *(const s16x8*)&Ws[c0][k0];
    s16x8 bf1 = *(const s16x8*)&Ws[c1][k0];
#pragma unroll
    for (int m = 0; m < 4; ++m) {
      s16x8 a = *(const s16x8*)&Xs[m * 16 + lr][k0];
      acc[m][0] = __builtin_amdgcn_mfma_f32_16x16x32_bf16(a, bf0, acc[m][0], 0, 0, 0);
      acc[m][1] = __builtin_amdgcn_mfma_f32_16x16x32_bf16(a, bf1, acc[m][1], 0, 0, 0);
    }
  }
  float bias1_0 = b1g[c0], bias1_1 = b1g[c1];
  __syncthreads();

#pragma unroll
  for (int m = 0; m < 4; ++m)
#pragma unroll
    for (int r2 = 0; r2 < 4; ++r2) {
      int row = m * 16 + lg * 4 + r2;
      Hs[row][c0] = f2bf(fmaxf(acc[m][0][r2] + bias1_0, 0.f));
      Hs[row][c1] = f2bf(fmaxf(acc[m][1][r2] + bias1_1, 0.f));
    }
  for (int u = tid; u < 128 * 16; u += 256) {
    int r = u >> 4, c = u & 15;
    *(int4*)&W2s[r][c * 8] = *(const int4*)(w2t + r * 128 + c * 8);
  }
  __syncthreads();

  f32x4 acc2[4][2] = {};
  for (int kk = 0; kk < 4; ++kk) {
    int k0 = kk * 32 + koff;
    s16x8 bf0 = *(const s16x8*)&W2s[c0][k0];
    s16x8 bf1 = *(const s16x8*)&W2s[c1][k0];
#pragma unroll
    for (int m = 0; m < 4; ++m) {
      s16x8 a = *(const s16x8*)&Hs[m * 16 + lr][k0];
      acc2[m][0] = __builtin_amdgcn_mfma_f32_16x16x32_bf16(a, bf0, acc2[m][0], 0, 0, 0);
      acc2[m][1] = __builtin_amdgcn_mfma_f32_16x16x32_bf16(a, bf1, acc2[m][1], 0, 0, 0);
    }
  }
  float bias2_0 = b2g[c0], bias2_1 = b2g[c1];

  // residual add, park x in LDS (fp32)
#pragma unroll
  for (int m = 0; m < 4; ++m)
#pragma unroll
    for (int r2 = 0; r2 < 4; ++r2) {
      int row = m * 16 + lg * 4 + r2;
      long node = base + row;
      float h0 = 0.f, h1 = 0.f;
      if (node < NNODES) { h0 = h[node * 128 + c0]; h1 = h[node * 128 + c1]; }
      Xf[row][c0] = acc2[m][0][r2] + bias2_0 + h0;
      Xf[row][c1] = acc2[m][1][r2] + bias2_1 + h1;
    }
  __syncthreads();

  // LayerNorm: 4 lanes per row
  int r = tid >> 2, q = tid & 3;
  float sum = 0.f, ss = 0.f;
  float4 vals[8];
#pragma unroll
  for (int j = 0; j < 8; ++j) {
    float4 v = *(const float4*)&Xf[r][q * 32 + j * 4];
    vals[j] = v;
    sum += v.x + v.y + v.z + v.w;
    ss += v.x * v.x + v.y * v.y + v.z * v.z + v.w * v.w;
  }
  sum += __shfl_xor(sum, 1); sum += __shfl_xor(sum, 2);
  ss  += __shfl_xor(ss, 1);  ss  += __shfl_xor(ss, 2);
  float mean = sum * (1.f / 128.f);
  float var = ss * (1.f / 128.f) - mean * mean;
  float rstd = rsqrtf(var + 1e-5f);
  long node = base + r;
  if (node < NNODES) {
#pragma unroll
    for (int j = 0; j < 8; ++j) {
      int cc = q * 32 + j * 4;
      float4 v = vals[j];
      float4 o;
      o.x = (v.x - mean) * rstd * lng[cc + 0] + lnb[cc + 0];
      o.y = (v.y - mean) * rstd * lng[cc + 1] + lnb[cc + 1];
      o.z = (v.z - mean) * rstd * lng[cc + 2] + lnb[cc + 2];
      o.w = (v.w - mean) * rstd * lng[cc + 3] + lnb[cc + 3];
      *(float4*)(out + node * 128 + cc) = o;
    }
  }
}

extern "C" void kernel_launch(void* const* d_in, const int* in_sizes, int n_in,
                              void* d_out, int out_size, void* d_ws, size_t ws_size,
                              hipStream_t stream) {
  const float* h    = (const float*)d_in[0];
  const int*   ei   = (const int*)d_in[1];
  const float* ex   = (const float*)d_in[2];
  const float* epw1 = (const float*)d_in[3];
  const float* epb1 = (const float*)d_in[4];
  const float* epw2 = (const float*)d_in[5];
  const float* epb2 = (const float*)d_in[6];
  const float* upw1 = (const float*)d_in[7];
  const float* upb1 = (const float*)d_in[8];
  const float* upw2 = (const float*)d_in[9];
  const float* upb2 = (const float*)d_in[10];
  const float* lng  = (const float*)d_in[11];
  const float* lnb  = (const float*)d_in[12];
  float* out = (float*)d_out;

  char* ws = (char*)d_ws;
  float* inc    = (float*)(ws);                 // 51,200,000 B
  float* outg   = (float*)(ws + 51200000);      // 51,200,000 B
  float* indeg  = (float*)(ws + 102400000);     // 400,000 B
  float* outdeg = (float*)(ws + 102800000);     // 400,000 B
  short* hb     = (short*)(ws + 103200000);     // 25,600,000 B
  short* w1et   = (short*)(ws + 128800000);     // 98,304 B
  short* w2et   = (short*)(ws + 128898304);     // 32,768 B
  short* w1ut   = (short*)(ws + 128931072);     // 98,304 B
  short* w2ut   = (short*)(ws + 129029376);     // 32,768 B

  hipMemsetAsync(ws, 0, 103200000, stream);     // inc+outg+degs
  hipLaunchKernelGGL(k_prep_h, dim3(2048), dim3(256), 0, stream,
                     (const float4*)h, (short4*)hb, NNODES * 128 / 4);
  hipLaunchKernelGGL(k_prep_w, dim3(256), dim3(256), 0, stream,
                     epw1, epw2, upw1, upw2, w1et, w2et, w1ut, w2ut);
  hipLaunchKernelGGL(k_edge, dim3(NEDGES / 64), dim3(256), 0, stream,
                     hb, ei, ex, w1et, w2et, epb1, epb2, inc, outg, indeg, outdeg);
  hipLaunchKernelGGL(k_node, dim3((NNODES + 63) / 64), dim3(256), 0, stream,
                     h, inc, outg, indeg, outdeg, w1ut, w2ut, upb1, upb2, lng, lnb, out);
}

// Round 2
// 914.837 us; speedup vs baseline: 1.4680x; 1.4680x over previous
//
#include <hip/hip_runtime.h>
#include <stdint.h>

#define HIDD 128
#define NNODES 100000
#define NEDGES 800000

typedef short s16x8 __attribute__((ext_vector_type(8)));
typedef float f32x4 __attribute__((ext_vector_type(4)));

__device__ __forceinline__ short f2bf(float f) {
  union { float f; unsigned u; } v; v.f = f;
  return (short)((v.u + 0x7fffu + ((v.u >> 16) & 1u)) >> 16);
}
__device__ __forceinline__ short4 cvt4(float4 v) {
  short4 s; s.x = f2bf(v.x); s.y = f2bf(v.y); s.z = f2bf(v.z); s.w = f2bf(v.w);
  return s;
}
__device__ __forceinline__ f32x4 mfma16(s16x8 a, s16x8 b, f32x4 c) {
  return __builtin_amdgcn_mfma_f32_16x16x32_bf16(a, b, c, 0, 0, 0);
}

// ---------- prep: h -> bf16 ----------
__global__ void k_prep_h(const float4* __restrict__ h4, short4* __restrict__ hb4, int n4) {
  int stride = gridDim.x * blockDim.x;
  for (int i = blockIdx.x * blockDim.x + threadIdx.x; i < n4; i += stride)
    hb4[i] = cvt4(h4[i]);
}

// ---------- prep: weights -> bf16, transposed to [out][in] ----------
__global__ void k_prep_w(const float* __restrict__ w1e, const float* __restrict__ w2e,
                         const float* __restrict__ w1u, const float* __restrict__ w2u,
                         short* __restrict__ w1et, short* __restrict__ w2et,
                         short* __restrict__ w1ut, short* __restrict__ w2ut) {
  int i = blockIdx.x * 256 + threadIdx.x;
  if (i < 49152) {               // [384][128] -> [128][384]
    int k = i >> 7, n = i & 127;
    w1et[n * 384 + k] = f2bf(w1e[i]);
    w1ut[n * 384 + k] = f2bf(w1u[i]);
  } else {
    int j = i - 49152;
    if (j < 16384) {             // [128][128] -> [128][128]
      int k = j >> 7, n = j & 127;
      w2et[n * 128 + k] = f2bf(w2e[j]);
      w2ut[n * 128 + k] = f2bf(w2u[j]);
    }
  }
}

// ---------- edge: weights-in-registers, grid-stride over 64-edge tiles ----------
// LDS 67584 B -> 2 blocks/CU (8 waves/CU). 2 barriers per tile.
__global__ __launch_bounds__(256, 2)
void k_edge(const short* __restrict__ hb, const int* __restrict__ eidx,
            const float* __restrict__ ex,
            const short* __restrict__ w1t, const short* __restrict__ w2t,
            const float* __restrict__ b1g, const float* __restrict__ b2g,
            float* __restrict__ inc, float* __restrict__ outg,
            float* __restrict__ indeg, float* __restrict__ outdeg) {
  __shared__ __align__(16) short Xs[64][392];   // 50176 B
  __shared__ __align__(16) short Hs[64][136];   // 17408 B

  const int tid = threadIdx.x;
  const int wave = tid >> 6, lane = tid & 63;
  const int lg = lane >> 4, lr = lane & 15;
  const int koff = lg * 8;
  const int c0 = wave * 32 + lr, c1 = c0 + 16;

  // per-lane weight fragments: 24 + 8 s16x8 = 128 VGPRs, loaded once per block
  s16x8 wb1a[12], wb1b[12], wb2a[4], wb2b[4];
#pragma unroll
  for (int kk = 0; kk < 12; ++kk) {
    wb1a[kk] = *(const s16x8*)(w1t + c0 * 384 + kk * 32 + koff);
    wb1b[kk] = *(const s16x8*)(w1t + c1 * 384 + kk * 32 + koff);
  }
#pragma unroll
  for (int kk = 0; kk < 4; ++kk) {
    wb2a[kk] = *(const s16x8*)(w2t + c0 * 128 + kk * 32 + koff);
    wb2b[kk] = *(const s16x8*)(w2t + c1 * 128 + kk * 32 + koff);
  }
  const float bias1_0 = b1g[c0], bias1_1 = b1g[c1];
  const float bias2_0 = b2g[c0], bias2_1 = b2g[c1];

  for (int t = blockIdx.x; t < NEDGES / 64; t += gridDim.x) {
    const int base = t * 64;

    // Phase A: gather h[src]|h[dst] (bf16) and edge_x (f32->bf16) into Xs
    for (int u = tid; u < 64 * 32; u += 256) {
      int r = u >> 5, c = u & 31;
      int node = (c < 16) ? eidx[base + r] : eidx[NEDGES + base + r];
      *(int4*)&Xs[r][c * 8] = *(const int4*)(hb + (long)node * 128 + (c & 15) * 8);
    }
    for (int u = tid; u < 64 * 32; u += 256) {
      int r = u >> 5, q = u & 31;
      float4 v = *(const float4*)(ex + (long)(base + r) * 128 + q * 4);
      *(short4*)&Xs[r][256 + q * 4] = cvt4(v);
    }
    if (tid < 64) {
      atomicAdd(&outdeg[eidx[base + tid]], 1.0f);
      atomicAdd(&indeg[eidx[NEDGES + base + tid]], 1.0f);
    }
    __syncthreads();

    // Phase B: layer 1 [64,384]@[384,128], bias+relu -> Hs (bf16)
    f32x4 acc[4][2] = {};
#pragma unroll
    for (int kk = 0; kk < 12; ++kk) {
      int k0 = kk * 32 + koff;
#pragma unroll
      for (int m = 0; m < 4; ++m) {
        s16x8 a = *(const s16x8*)&Xs[m * 16 + lr][k0];
        acc[m][0] = mfma16(a, wb1a[kk], acc[m][0]);
        acc[m][1] = mfma16(a, wb1b[kk], acc[m][1]);
      }
    }
#pragma unroll
    for (int m = 0; m < 4; ++m)
#pragma unroll
      for (int r2 = 0; r2 < 4; ++r2) {
        int row = m * 16 + lg * 4 + r2;
        Hs[row][c0] = f2bf(fmaxf(acc[m][0][r2] + bias1_0, 0.f));
        Hs[row][c1] = f2bf(fmaxf(acc[m][1][r2] + bias1_1, 0.f));
      }
    __syncthreads();   // Hs ready; also implies all waves done reading Xs

    // Phase C: layer 2 [64,128]@[128,128] + atomic scatter
    f32x4 acc2[4][2] = {};
#pragma unroll
    for (int kk = 0; kk < 4; ++kk) {
      int k0 = kk * 32 + koff;
#pragma unroll
      for (int m = 0; m < 4; ++m) {
        s16x8 a = *(const s16x8*)&Hs[m * 16 + lr][k0];
        acc2[m][0] = mfma16(a, wb2a[kk], acc2[m][0]);
        acc2[m][1] = mfma16(a, wb2b[kk], acc2[m][1]);
      }
    }
#pragma unroll
    for (int m = 0; m < 4; ++m)
#pragma unroll
      for (int r2 = 0; r2 < 4; ++r2) {
        int row = m * 16 + lg * 4 + r2;
        int s = eidx[base + row], d = eidx[NEDGES + base + row];
        float v0 = acc2[m][0][r2] + bias2_0;
        float v1 = acc2[m][1][r2] + bias2_1;
        atomicAdd(&outg[(long)s * 128 + c0], v0);
        atomicAdd(&outg[(long)s * 128 + c1], v1);
        atomicAdd(&inc[(long)d * 128 + c0], v0);
        atomicAdd(&inc[(long)d * 128 + c1], v1);
      }
    // no barrier: next Phase A only writes Xs, whose last readers (Phase B)
    // all retired before the Hs-ready barrier above.
  }
}

// ---------- node: same template + residual + LayerNorm ----------
__global__ __launch_bounds__(256, 2)
void k_node(const float* __restrict__ h, const float* __restrict__ inc,
            const float* __restrict__ outg, const float* __restrict__ indeg,
            const float* __restrict__ outdeg,
            const short* __restrict__ w1t, const short* __restrict__ w2t,
            const float* __restrict__ b1g, const float* __restrict__ b2g,
            const float* __restrict__ lng, const float* __restrict__ lnb,
            float* __restrict__ out) {
  __shared__ __align__(16) char smem[67584];
  short (*Xs)[392] = (short (*)[392])smem;            // 50176 B
  float (*Xf)[132] = (float (*)[132])smem;            // 33792 B, overlays Xs
  short (*Hs)[136] = (short (*)[136])(smem + 50176);  // 17408 B

  const int tid = threadIdx.x;
  const int wave = tid >> 6, lane = tid & 63;
  const int lg = lane >> 4, lr = lane & 15;
  const int koff = lg * 8;
  const int c0 = wave * 32 + lr, c1 = c0 + 16;

  s16x8 wb1a[12], wb1b[12], wb2a[4], wb2b[4];
#pragma unroll
  for (int kk = 0; kk < 12; ++kk) {
    wb1a[kk] = *(const s16x8*)(w1t + c0 * 384 + kk * 32 + koff);
    wb1b[kk] = *(const s16x8*)(w1t + c1 * 384 + kk * 32 + koff);
  }
#pragma unroll
  for (int kk = 0; kk < 4; ++kk) {
    wb2a[kk] = *(const s16x8*)(w2t + c0 * 128 + kk * 32 + koff);
    wb2b[kk] = *(const s16x8*)(w2t + c1 * 128 + kk * 32 + koff);
  }
  const float bias1_0 = b1g[c0], bias1_1 = b1g[c1];
  const float bias2_0 = b2g[c0], bias2_1 = b2g[c1];

  const int ntiles = (NNODES + 63) / 64;
  for (int t = blockIdx.x; t < ntiles; t += gridDim.x) {
    const int base = t * 64;

    // Phase A: X = [h | inc/deg | outg/deg] -> bf16 LDS
    for (int u = tid; u < 64 * 32; u += 256) {
      int r = u >> 5, q = u & 31;
      long node = min(base + r, NNODES - 1);
      float4 v = *(const float4*)(h + node * 128 + q * 4);
      *(short4*)&Xs[r][q * 4] = cvt4(v);
    }
    for (int u = tid; u < 64 * 32; u += 256) {
      int r = u >> 5, q = u & 31;
      long node = min(base + r, NNODES - 1);
      float s = 1.f / fmaxf(indeg[node], 1.f);
      float4 v = *(const float4*)(inc + node * 128 + q * 4);
      v.x *= s; v.y *= s; v.z *= s; v.w *= s;
      *(short4*)&Xs[r][128 + q * 4] = cvt4(v);
    }
    for (int u = tid; u < 64 * 32; u += 256) {
      int r = u >> 5, q = u & 31;
      long node = min(base + r, NNODES - 1);
      float s = 1.f / fmaxf(outdeg[node], 1.f);
      float4 v = *(const float4*)(outg + node * 128 + q * 4);
      v.x *= s; v.y *= s; v.z *= s; v.w *= s;
      *(short4*)&Xs[r][256 + q * 4] = cvt4(v);
    }
    __syncthreads();

    // Phase B: layer 1
    f32x4 acc[4][2] = {};
#pragma unroll
    for (int kk = 0; kk < 12; ++kk) {
      int k0 = kk * 32 + koff;
#pragma unroll
      for (int m = 0; m < 4; ++m) {
        s16x8 a = *(const s16x8*)&Xs[m * 16 + lr][k0];
        acc[m][0] = mfma16(a, wb1a[kk], acc[m][0]);
        acc[m][1] = mfma16(a, wb1b[kk], acc[m][1]);
      }
    }
#pragma unroll
    for (int m = 0; m < 4; ++m)
#pragma unroll
      for (int r2 = 0; r2 < 4; ++r2) {
        int row = m * 16 + lg * 4 + r2;
        Hs[row][c0] = f2bf(fmaxf(acc[m][0][r2] + bias1_0, 0.f));
        Hs[row][c1] = f2bf(fmaxf(acc[m][1][r2] + bias1_1, 0.f));
      }
    __syncthreads();   // Hs ready + Xs reads retired

    // Phase C: layer 2, residual, park x (f32) in Xf
    f32x4 acc2[4][2] = {};
#pragma unroll
    for (int kk = 0; kk < 4; ++kk) {
      int k0 = kk * 32 + koff;
#pragma unroll
      for (int m = 0; m < 4; ++m) {
        s16x8 a = *(const s16x8*)&Hs[m * 16 + lr][k0];
        acc2[m][0] = mfma16(a, wb2a[kk], acc2[m][0]);
        acc2[m][1] = mfma16(a, wb2b[kk], acc2[m][1]);
      }
    }
#pragma unroll
    for (int m = 0; m < 4; ++m)
#pragma unroll
      for (int r2 = 0; r2 < 4; ++r2) {
        int row = m * 16 + lg * 4 + r2;
        long node = base + row;
        float h0 = 0.f, h1 = 0.f;
        if (node < NNODES) { h0 = h[node * 128 + c0]; h1 = h[node * 128 + c1]; }
        Xf[row][c0] = acc2[m][0][r2] + bias2_0 + h0;
        Xf[row][c1] = acc2[m][1][r2] + bias2_1 + h1;
      }
    __syncthreads();

    // Phase D: LayerNorm (4 lanes per row) + store
    {
      int r = tid >> 2, q = tid & 3;
      float sum = 0.f, ss = 0.f;
      float4 vals[8];
#pragma unroll
      for (int j = 0; j < 8; ++j) {
        float4 v = *(const float4*)&Xf[r][q * 32 + j * 4];
        vals[j] = v;
        sum += v.x + v.y + v.z + v.w;
        ss += v.x * v.x + v.y * v.y + v.z * v.z + v.w * v.w;
      }
      sum += __shfl_xor(sum, 1); sum += __shfl_xor(sum, 2);
      ss  += __shfl_xor(ss, 1);  ss  += __shfl_xor(ss, 2);
      float mean = sum * (1.f / 128.f);
      float var = ss * (1.f / 128.f) - mean * mean;
      float rstd = rsqrtf(var + 1e-5f);
      long node = base + r;
      if (node < NNODES) {
#pragma unroll
        for (int j = 0; j < 8; ++j) {
          int cc = q * 32 + j * 4;
          float4 v = vals[j];
          float4 o;
          o.x = (v.x - mean) * rstd * lng[cc + 0] + lnb[cc + 0];
          o.y = (v.y - mean) * rstd * lng[cc + 1] + lnb[cc + 1];
          o.z = (v.z - mean) * rstd * lng[cc + 2] + lnb[cc + 2];
          o.w = (v.w - mean) * rstd * lng[cc + 3] + lnb[cc + 3];
          *(float4*)(out + node * 128 + cc) = o;
        }
      }
    }
    __syncthreads();   // protect Xf from next tile's Xs writes
  }
}

extern "C" void kernel_launch(void* const* d_in, const int* in_sizes, int n_in,
                              void* d_out, int out_size, void* d_ws, size_t ws_size,
                              hipStream_t stream) {
  const float* h    = (const float*)d_in[0];
  const int*   ei   = (const int*)d_in[1];
  const float* ex   = (const float*)d_in[2];
  const float* epw1 = (const float*)d_in[3];
  const float* epb1 = (const float*)d_in[4];
  const float* epw2 = (const float*)d_in[5];
  const float* epb2 = (const float*)d_in[6];
  const float* upw1 = (const float*)d_in[7];
  const float* upb1 = (const float*)d_in[8];
  const float* upw2 = (const float*)d_in[9];
  const float* upb2 = (const float*)d_in[10];
  const float* lng  = (const float*)d_in[11];
  const float* lnb  = (const float*)d_in[12];
  float* out = (float*)d_out;

  char* ws = (char*)d_ws;
  float* inc    = (float*)(ws);                 // 51,200,000 B
  float* outg   = (float*)(ws + 51200000);      // 51,200,000 B
  float* indeg  = (float*)(ws + 102400000);     // 400,000 B
  float* outdeg = (float*)(ws + 102800000);     // 400,000 B
  short* hb     = (short*)(ws + 103200000);     // 25,600,000 B
  short* w1et   = (short*)(ws + 128800000);     // 98,304 B
  short* w2et   = (short*)(ws + 128898304);     // 32,768 B
  short* w1ut   = (short*)(ws + 128931072);     // 98,304 B
  short* w2ut   = (short*)(ws + 129029376);     // 32,768 B

  hipMemsetAsync(ws, 0, 103200000, stream);     // inc+outg+degs
  hipLaunchKernelGGL(k_prep_h, dim3(2048), dim3(256), 0, stream,
                     (const float4*)h, (short4*)hb, NNODES * 128 / 4);
  hipLaunchKernelGGL(k_prep_w, dim3(256), dim3(256), 0, stream,
                     epw1, epw2, upw1, upw2, w1et, w2et, w1ut, w2ut);
  hipLaunchKernelGGL(k_edge, dim3(1024), dim3(256), 0, stream,
                     hb, ei, ex, w1et, w2et, epb1, epb2, inc, outg, indeg, outdeg);
  hipLaunchKernelGGL(k_node, dim3(512), dim3(256), 0, stream,
                     h, inc, outg, indeg, outdeg, w1ut, w2ut, upb1, upb2, lng, lnb, out);
}

// Round 3
// 681.741 us; speedup vs baseline: 1.9700x; 1.3419x over previous
//
#include <hip/hip_runtime.h>
#include <stdint.h>

#define HIDD 128
#define NNODES 100000
#define NEDGES 800000

typedef short s16x8 __attribute__((ext_vector_type(8)));
typedef float f32x4 __attribute__((ext_vector_type(4)));

__device__ __forceinline__ short f2bf(float f) {
  union { float f; unsigned u; } v; v.f = f;
  return (short)((v.u + 0x7fffu + ((v.u >> 16) & 1u)) >> 16);
}
__device__ __forceinline__ short4 cvt4(float4 v) {
  short4 s; s.x = f2bf(v.x); s.y = f2bf(v.y); s.z = f2bf(v.z); s.w = f2bf(v.w);
  return s;
}
__device__ __forceinline__ float bflo(unsigned w) {
  union { unsigned u; float f; } v; v.u = w << 16; return v.f;
}
__device__ __forceinline__ float bfhi(unsigned w) {
  union { unsigned u; float f; } v; v.u = w & 0xffff0000u; return v.f;
}
__device__ __forceinline__ unsigned pack2(float a, float b) {
  return ((unsigned)(unsigned short)f2bf(b) << 16) | (unsigned)(unsigned short)f2bf(a);
}
__device__ __forceinline__ f32x4 mfma16(s16x8 a, s16x8 b, f32x4 c) {
  return __builtin_amdgcn_mfma_f32_16x16x32_bf16(a, b, c, 0, 0, 0);
}
// packed bf16x2 atomic add (one dword RMW at the TCC)
__device__ __forceinline__ void atomic_pk_bf16(unsigned short* addr, unsigned pk) {
  asm volatile("global_atomic_pk_add_bf16 %0, %1, off" :: "v"(addr), "v"(pk) : "memory");
}

// ---------- prep: h -> bf16 ----------
__global__ void k_prep_h(const float4* __restrict__ h4, short4* __restrict__ hb4, int n4) {
  int stride = gridDim.x * blockDim.x;
  for (int i = blockIdx.x * blockDim.x + threadIdx.x; i < n4; i += stride)
    hb4[i] = cvt4(h4[i]);
}

// ---------- prep: weights -> bf16 [out][in]; w2e additionally col-permuted ----------
// w2et storage row n holds original output col (n & ~31) + 2*(n&15) + ((n>>4)&1),
// so that in k_edge, lane lr / n-tile t yields physical col wave*32 + 2*lr + t.
__global__ void k_prep_w(const float* __restrict__ w1e, const float* __restrict__ w2e,
                         const float* __restrict__ w1u, const float* __restrict__ w2u,
                         short* __restrict__ w1et, short* __restrict__ w2et,
                         short* __restrict__ w1ut, short* __restrict__ w2ut) {
  int i = blockIdx.x * 256 + threadIdx.x;
  if (i < 49152) {               // dest [128][384]: n=i/384, k=i%384
    int n = i / 384, k = i - n * 384;
    w1et[i] = f2bf(w1e[k * 128 + n]);
    w1ut[i] = f2bf(w1u[k * 128 + n]);
  } else {
    int j = i - 49152;
    if (j < 16384) {             // dest [128][128]: n=j>>7, k=j&127
      int n = j >> 7, k = j & 127;
      int oc = (n & ~31) + 2 * (n & 15) + ((n >> 4) & 1);
      w2et[j] = f2bf(w2e[k * 128 + oc]);   // permuted for pk-atomic epilogue
      w2ut[j] = f2bf(w2u[k * 128 + n]);    // natural
    }
  }
}

// ---------- edge: weights-in-registers, grid-stride tiles, pk-bf16 atomic scatter ----------
__global__ __launch_bounds__(256, 2)
void k_edge(const short* __restrict__ hb, const int* __restrict__ eidx,
            const float* __restrict__ ex,
            const short* __restrict__ w1t, const short* __restrict__ w2t,
            const float* __restrict__ b1g, const float* __restrict__ b2g,
            unsigned short* __restrict__ incb, unsigned short* __restrict__ outgb,
            float* __restrict__ indeg, float* __restrict__ outdeg) {
  __shared__ __align__(16) short Xs[64][392];   // 50176 B
  __shared__ __align__(16) short Hs[64][136];   // 17408 B

  const int tid = threadIdx.x;
  const int wave = tid >> 6, lane = tid & 63;
  const int lg = lane >> 4, lr = lane & 15;
  const int koff = lg * 8;
  const int c0 = wave * 32 + lr, c1 = c0 + 16;   // layer-1 (natural) cols
  const int pc0 = wave * 32 + 2 * lr;            // layer-2 physical col (even)

  s16x8 wb1a[12], wb1b[12], wb2a[4], wb2b[4];
#pragma unroll
  for (int kk = 0; kk < 12; ++kk) {
    wb1a[kk] = *(const s16x8*)(w1t + c0 * 384 + kk * 32 + koff);
    wb1b[kk] = *(const s16x8*)(w1t + c1 * 384 + kk * 32 + koff);
  }
#pragma unroll
  for (int kk = 0; kk < 4; ++kk) {
    wb2a[kk] = *(const s16x8*)(w2t + c0 * 128 + kk * 32 + koff);
    wb2b[kk] = *(const s16x8*)(w2t + c1 * 128 + kk * 32 + koff);
  }
  const float bias1_0 = b1g[c0], bias1_1 = b1g[c1];
  const float bias2_0 = b2g[pc0], bias2_1 = b2g[pc0 + 1];

  for (int t = blockIdx.x; t < NEDGES / 64; t += gridDim.x) {
    const int base = t * 64;

    // Phase A: gather h[src]|h[dst] (bf16) and edge_x (f32->bf16) into Xs
    for (int u = tid; u < 64 * 32; u += 256) {
      int r = u >> 5, c = u & 31;
      int node = (c < 16) ? eidx[base + r] : eidx[NEDGES + base + r];
      *(int4*)&Xs[r][c * 8] = *(const int4*)(hb + (long)node * 128 + (c & 15) * 8);
    }
    for (int u = tid; u < 64 * 32; u += 256) {
      int r = u >> 5, q = u & 31;
      float4 v = *(const float4*)(ex + (long)(base + r) * 128 + q * 4);
      *(short4*)&Xs[r][256 + q * 4] = cvt4(v);
    }
    if (tid < 64) {
      atomicAdd(&outdeg[eidx[base + tid]], 1.0f);
      atomicAdd(&indeg[eidx[NEDGES + base + tid]], 1.0f);
    }
    __syncthreads();

    // Phase B: layer 1 [64,384]@[384,128], bias+relu -> Hs (bf16)
    f32x4 acc[4][2] = {};
#pragma unroll
    for (int kk = 0; kk < 12; ++kk) {
      int k0 = kk * 32 + koff;
#pragma unroll
      for (int m = 0; m < 4; ++m) {
        s16x8 a = *(const s16x8*)&Xs[m * 16 + lr][k0];
        acc[m][0] = mfma16(a, wb1a[kk], acc[m][0]);
        acc[m][1] = mfma16(a, wb1b[kk], acc[m][1]);
      }
    }
#pragma unroll
    for (int m = 0; m < 4; ++m)
#pragma unroll
      for (int r2 = 0; r2 < 4; ++r2) {
        int row = m * 16 + lg * 4 + r2;
        Hs[row][c0] = f2bf(fmaxf(acc[m][0][r2] + bias1_0, 0.f));
        Hs[row][c1] = f2bf(fmaxf(acc[m][1][r2] + bias1_1, 0.f));
      }
    __syncthreads();   // Hs ready; Xs reads retired

    // Phase C: layer 2 (col-permuted W2) + pk-bf16 atomic scatter
    f32x4 acc2[4][2] = {};
#pragma unroll
    for (int kk = 0; kk < 4; ++kk) {
      int k0 = kk * 32 + koff;
#pragma unroll
      for (int m = 0; m < 4; ++m) {
        s16x8 a = *(const s16x8*)&Hs[m * 16 + lr][k0];
        acc2[m][0] = mfma16(a, wb2a[kk], acc2[m][0]);
        acc2[m][1] = mfma16(a, wb2b[kk], acc2[m][1]);
      }
    }
#pragma unroll
    for (int m = 0; m < 4; ++m)
#pragma unroll
      for (int r2 = 0; r2 < 4; ++r2) {
        int row = m * 16 + lg * 4 + r2;
        int s = eidx[base + row], d = eidx[NEDGES + base + row];
        unsigned pk = pack2(acc2[m][0][r2] + bias2_0, acc2[m][1][r2] + bias2_1);
        atomic_pk_bf16(outgb + (long)s * 128 + pc0, pk);
        atomic_pk_bf16(incb + (long)d * 128 + pc0, pk);
      }
    // no barrier needed before next Phase A (see Hs barrier above)
  }
}

// ---------- node: X=[hb | inc/deg | outg/deg] -> MLP -> residual+LN ----------
__global__ __launch_bounds__(256, 2)
void k_node(const float* __restrict__ h, const short* __restrict__ hb,
            const unsigned short* __restrict__ incb,
            const unsigned short* __restrict__ outgb,
            const float* __restrict__ indeg, const float* __restrict__ outdeg,
            const short* __restrict__ w1t, const short* __restrict__ w2t,
            const float* __restrict__ b1g, const float* __restrict__ b2g,
            const float* __restrict__ lng, const float* __restrict__ lnb,
            float* __restrict__ out) {
  __shared__ __align__(16) char smem[67584];
  short (*Xs)[392] = (short (*)[392])smem;            // 50176 B
  float (*Xf)[132] = (float (*)[132])smem;            // 33792 B, overlays Xs
  short (*Hs)[136] = (short (*)[136])(smem + 50176);  // 17408 B

  const int tid = threadIdx.x;
  const int wave = tid >> 6, lane = tid & 63;
  const int lg = lane >> 4, lr = lane & 15;
  const int koff = lg * 8;
  const int c0 = wave * 32 + lr, c1 = c0 + 16;

  s16x8 wb1a[12], wb1b[12], wb2a[4], wb2b[4];
#pragma unroll
  for (int kk = 0; kk < 12; ++kk) {
    wb1a[kk] = *(const s16x8*)(w1t + c0 * 384 + kk * 32 + koff);
    wb1b[kk] = *(const s16x8*)(w1t + c1 * 384 + kk * 32 + koff);
  }
#pragma unroll
  for (int kk = 0; kk < 4; ++kk) {
    wb2a[kk] = *(const s16x8*)(w2t + c0 * 128 + kk * 32 + koff);
    wb2b[kk] = *(const s16x8*)(w2t + c1 * 128 + kk * 32 + koff);
  }
  const float bias1_0 = b1g[c0], bias1_1 = b1g[c1];
  const float bias2_0 = b2g[c0], bias2_1 = b2g[c1];

  const int ntiles = (NNODES + 63) / 64;
  for (int t = blockIdx.x; t < ntiles; t += gridDim.x) {
    const int base = t * 64;

    // Phase A: X = [hb | incb/deg | outgb/deg] -> bf16 LDS
    for (int u = tid; u < 64 * 16; u += 256) {     // hb straight copy
      int r = u >> 4, c = u & 15;
      long node = min(base + r, NNODES - 1);
      *(int4*)&Xs[r][c * 8] = *(const int4*)(hb + node * 128 + c * 8);
    }
    for (int u = tid; u < 64 * 16; u += 256) {     // incb scaled
      int r = u >> 4, c = u & 15;
      long node = min(base + r, NNODES - 1);
      float s = 1.f / fmaxf(indeg[node], 1.f);
      uint4 w = *(const uint4*)(incb + node * 128 + c * 8);
      unsigned o0 = pack2(bflo(w.x) * s, bfhi(w.x) * s);
      unsigned o1 = pack2(bflo(w.y) * s, bfhi(w.y) * s);
      unsigned o2 = pack2(bflo(w.z) * s, bfhi(w.z) * s);
      unsigned o3 = pack2(bflo(w.w) * s, bfhi(w.w) * s);
      *(uint4*)&Xs[r][128 + c * 8] = make_uint4(o0, o1, o2, o3);
    }
    for (int u = tid; u < 64 * 16; u += 256) {     // outgb scaled
      int r = u >> 4, c = u & 15;
      long node = min(base + r, NNODES - 1);
      float s = 1.f / fmaxf(outdeg[node], 1.f);
      uint4 w = *(const uint4*)(outgb + node * 128 + c * 8);
      unsigned o0 = pack2(bflo(w.x) * s, bfhi(w.x) * s);
      unsigned o1 = pack2(bflo(w.y) * s, bfhi(w.y) * s);
      unsigned o2 = pack2(bflo(w.z) * s, bfhi(w.z) * s);
      unsigned o3 = pack2(bflo(w.w) * s, bfhi(w.w) * s);
      *(uint4*)&Xs[r][256 + c * 8] = make_uint4(o0, o1, o2, o3);
    }
    __syncthreads();

    // Phase B: layer 1
    f32x4 acc[4][2] = {};
#pragma unroll
    for (int kk = 0; kk < 12; ++kk) {
      int k0 = kk * 32 + koff;
#pragma unroll
      for (int m = 0; m < 4; ++m) {
        s16x8 a = *(const s16x8*)&Xs[m * 16 + lr][k0];
        acc[m][0] = mfma16(a, wb1a[kk], acc[m][0]);
        acc[m][1] = mfma16(a, wb1b[kk], acc[m][1]);
      }
    }
#pragma unroll
    for (int m = 0; m < 4; ++m)
#pragma unroll
      for (int r2 = 0; r2 < 4; ++r2) {
        int row = m * 16 + lg * 4 + r2;
        Hs[row][c0] = f2bf(fmaxf(acc[m][0][r2] + bias1_0, 0.f));
        Hs[row][c1] = f2bf(fmaxf(acc[m][1][r2] + bias1_1, 0.f));
      }
    __syncthreads();

    // Phase C: layer 2, residual, park x (f32) in Xf
    f32x4 acc2[4][2] = {};
#pragma unroll
    for (int kk = 0; kk < 4; ++kk) {
      int k0 = kk * 32 + koff;
#pragma unroll
      for (int m = 0; m < 4; ++m) {
        s16x8 a = *(const s16x8*)&Hs[m * 16 + lr][k0];
        acc2[m][0] = mfma16(a, wb2a[kk], acc2[m][0]);
        acc2[m][1] = mfma16(a, wb2b[kk], acc2[m][1]);
      }
    }
#pragma unroll
    for (int m = 0; m < 4; ++m)
#pragma unroll
      for (int r2 = 0; r2 < 4; ++r2) {
        int row = m * 16 + lg * 4 + r2;
        long node = base + row;
        float h0 = 0.f, h1 = 0.f;
        if (node < NNODES) { h0 = h[node * 128 + c0]; h1 = h[node * 128 + c1]; }
        Xf[row][c0] = acc2[m][0][r2] + bias2_0 + h0;
        Xf[row][c1] = acc2[m][1][r2] + bias2_1 + h1;
      }
    __syncthreads();

    // Phase D: LayerNorm (4 lanes per row) + store
    {
      int r = tid >> 2, q = tid & 3;
      float sum = 0.f, ss = 0.f;
      float4 vals[8];
#pragma unroll
      for (int j = 0; j < 8; ++j) {
        float4 v = *(const float4*)&Xf[r][q * 32 + j * 4];
        vals[j] = v;
        sum += v.x + v.y + v.z + v.w;
        ss += v.x * v.x + v.y * v.y + v.z * v.z + v.w * v.w;
      }
      sum += __shfl_xor(sum, 1); sum += __shfl_xor(sum, 2);
      ss  += __shfl_xor(ss, 1);  ss  += __shfl_xor(ss, 2);
      float mean = sum * (1.f / 128.f);
      float var = ss * (1.f / 128.f) - mean * mean;
      float rstd = rsqrtf(var + 1e-5f);
      long node = base + r;
      if (node < NNODES) {
#pragma unroll
        for (int j = 0; j < 8; ++j) {
          int cc = q * 32 + j * 4;
          float4 v = vals[j];
          float4 o;
          o.x = (v.x - mean) * rstd * lng[cc + 0] + lnb[cc + 0];
          o.y = (v.y - mean) * rstd * lng[cc + 1] + lnb[cc + 1];
          o.z = (v.z - mean) * rstd * lng[cc + 2] + lnb[cc + 2];
          o.w = (v.w - mean) * rstd * lng[cc + 3] + lnb[cc + 3];
          *(float4*)(out + node * 128 + cc) = o;
        }
      }
    }
    __syncthreads();   // protect Xf from next tile's Xs writes
  }
}

extern "C" void kernel_launch(void* const* d_in, const int* in_sizes, int n_in,
                              void* d_out, int out_size, void* d_ws, size_t ws_size,
                              hipStream_t stream) {
  const float* h    = (const float*)d_in[0];
  const int*   ei   = (const int*)d_in[1];
  const float* ex   = (const float*)d_in[2];
  const float* epw1 = (const float*)d_in[3];
  const float* epb1 = (const float*)d_in[4];
  const float* epw2 = (const float*)d_in[5];
  const float* epb2 = (const float*)d_in[6];
  const float* upw1 = (const float*)d_in[7];
  const float* upb1 = (const float*)d_in[8];
  const float* upw2 = (const float*)d_in[9];
  const float* upb2 = (const float*)d_in[10];
  const float* lng  = (const float*)d_in[11];
  const float* lnb  = (const float*)d_in[12];
  float* out = (float*)d_out;

  char* ws = (char*)d_ws;
  unsigned short* incb  = (unsigned short*)(ws);             // 25,600,000 B
  unsigned short* outgb = (unsigned short*)(ws + 25600000);  // 25,600,000 B
  float* indeg  = (float*)(ws + 51200000);                   //    400,000 B
  float* outdeg = (float*)(ws + 51600000);                   //    400,000 B
  short* hb     = (short*)(ws + 52000000);                   // 25,600,000 B
  short* w1et   = (short*)(ws + 77600000);                   //     98,304 B
  short* w2et   = (short*)(ws + 77698304);                   //     32,768 B
  short* w1ut   = (short*)(ws + 77731072);                   //     98,304 B
  short* w2ut   = (short*)(ws + 77829376);                   //     32,768 B

  hipMemsetAsync(ws, 0, 52000000, stream);   // incb+outgb+degrees
  hipLaunchKernelGGL(k_prep_h, dim3(2048), dim3(256), 0, stream,
                     (const float4*)h, (short4*)hb, NNODES * 128 / 4);
  hipLaunchKernelGGL(k_prep_w, dim3(256), dim3(256), 0, stream,
                     epw1, epw2, upw1, upw2, w1et, w2et, w1ut, w2ut);
  hipLaunchKernelGGL(k_edge, dim3(1024), dim3(256), 0, stream,
                     hb, ei, ex, w1et, w2et, epb1, epb2, incb, outgb, indeg, outdeg);
  hipLaunchKernelGGL(k_node, dim3(512), dim3(256), 0, stream,
                     h, hb, incb, outgb, indeg, outdeg, w1ut, w2ut, upb1, upb2,
                     lng, lnb, out);
}